// Round 2
// baseline (229.573 us; speedup 1.0000x reference)
//
#include <hip/hip_runtime.h>

#define HW 128
#define CCH 1280

// workspace layout (float indices)
#define OFF_TROW 0        // 65 taps, x-direction
#define OFF_TCOL 80       // 65 taps, y-direction
#define OFF_INTS 160      // int slots: 0:by0 1:by1 2:rad 3:Hb
#define OFF_B    256      // 128*128 row-dilated mask
#define OFF_REC  (256 + 16384)        // 128*128 reciprocal denominator
#define OFF_TMP  (256 + 2 * 16384)    // [C][Hb][128] row-conv intermediate

// ---------------------------------------------------------------------------
// Setup: composite 1D taps (20-fold self-conv of the 5-tap marginals) + row bbox
// ---------------------------------------------------------------------------
__global__ void k_setup(const float* __restrict__ mask, const float* __restrict__ fw,
                        const int* __restrict__ itp, float* __restrict__ ws) {
  __shared__ float cu[96], cv[96], nu[96], nv[96], su[8], sv[8], sinv[1];
  __shared__ int smn, smx;
  int t = threadIdx.x;  // 256 threads
  int iters = itp[0];
  if (iters > 20) iters = 20;
  if (iters < 1) iters = 1;
  if (t == 0) { smn = 1 << 30; smx = -1; }
  if (t < 5) {
    float ru = 0.f, rv = 0.f;
    for (int j = 0; j < 5; ++j) { ru += fw[t * 5 + j]; rv += fw[j * 5 + t]; }
    su[t] = ru; sv[t] = rv;  // W (rank-1) = su (y-dir) (x) sv/S (x-dir)
  }
  __syncthreads();
  if (t == 0) {
    float S = su[0] + su[1] + su[2] + su[3] + su[4];
    sinv[0] = (S != 0.f) ? 1.0f / S : 1.0f;
  }
  // bbox row scan of mask channel 0
  int mn = 1 << 30, mx = -1;
  for (int i = t; i < HW * HW; i += 256)
    if (mask[i] > 0.f) { int y = i >> 7; if (y < mn) mn = y; if (y > mx) mx = y; }
  __syncthreads();
  if (t < 5) sv[t] *= sinv[0];
  if (mx >= 0) { atomicMin(&smn, mn); atomicMax(&smx, mx); }
  if (t < 96) { cu[t] = (t == 40) ? 1.f : 0.f; cv[t] = (t == 40) ? 1.f : 0.f; }
  __syncthreads();
  for (int it = 0; it < iters; ++it) {
    if (t < 81) {
      float au = 0.f, av = 0.f;
      #pragma unroll
      for (int i = 0; i < 5; ++i) {
        int s = t - i + 2;
        if (s >= 0 && s <= 80) { au += su[i] * cu[s]; av += sv[i] * cv[s]; }
      }
      nu[t] = au; nv[t] = av;
    }
    __syncthreads();
    if (t < 81) { cu[t] = nu[t]; cv[t] = nv[t]; }
    __syncthreads();
  }
  if (t < 65) { ws[OFF_TCOL + t] = cu[t + 8]; ws[OFF_TROW + t] = cv[t + 8]; }
  if (t == 0) {
    int* wi = (int*)ws + OFF_INTS;
    int by0 = smn, by1 = smx;
    if (by1 < 0) { by0 = 0; by1 = -1; }
    wi[0] = by0; wi[1] = by1; wi[2] = 2 * (iters - 1); wi[3] = by1 - by0 + 1;
  }
}

// ---------------------------------------------------------------------------
// Row dilation of mask channel 0 by +/-rad (binary)
// ---------------------------------------------------------------------------
__global__ void k_rowdil(const float* __restrict__ mask, float* __restrict__ ws) {
  int y = blockIdx.x, x = threadIdx.x;
  int rad = ((const int*)ws)[OFF_INTS + 2];
  const float* row = mask + y * HW;
  int e0 = x - rad; if (e0 < 0) e0 = 0;
  int e1 = x + rad; if (e1 > HW - 1) e1 = HW - 1;
  float s = 0.f;
  for (int e = e0; e <= e1; ++e) s = fmaxf(s, row[e]);
  ws[OFF_B + y * HW + x] = (s > 0.f) ? 1.f : 0.f;
}

// ---------------------------------------------------------------------------
// Column dilation + 5x5 weighted count -> reciprocal denominator table
// ---------------------------------------------------------------------------
__global__ void k_rec(const float* __restrict__ mw, float* __restrict__ ws) {
  __shared__ float m19[5][HW];
  int y = blockIdx.x, x = threadIdx.x;
  int rad = ((const int*)ws)[OFF_INTS + 2];
  const float* b = ws + OFF_B;
  for (int k = 0; k < 5; ++k) {
    int yy = y + k - 2;
    float s = 0.f;
    if (yy >= 0 && yy < HW) {
      int e0 = yy - rad; if (e0 < 0) e0 = 0;
      int e1 = yy + rad; if (e1 > HW - 1) e1 = HW - 1;
      for (int e = e0; e <= e1; ++e) s = fmaxf(s, b[e * HW + x]);
    }
    m19[k][x] = (s > 0.f) ? 1.f : 0.f;
  }
  __syncthreads();
  float msum = 0.f;
  #pragma unroll
  for (int dy = 0; dy < 5; ++dy)
    #pragma unroll
    for (int dx = 0; dx < 5; ++dx) {
      int xx = x + dx - 2;
      if (xx >= 0 && xx < HW) msum += mw[dy * 5 + dx] * m19[dy][xx];
    }
  float d = (msum == 0.f) ? 1.f : msum;
  ws[OFF_REC + y * HW + x] = 1.0f / d;
}

// ---------------------------------------------------------------------------
// Pass A: 65-tap row conv of input*mask, bbox rows only -> compact tmp
// block = 256 threads = 16 rows x 16 x-segments(8 outputs each)
// ---------------------------------------------------------------------------
__global__ __launch_bounds__(256) void k_rowconv(const float* __restrict__ inp,
                                                 const float* __restrict__ mask,
                                                 const float* __restrict__ taps,
                                                 const int* __restrict__ wsi,
                                                 float* __restrict__ tmp) {
  int by0 = wsi[0], by1 = wsi[1], Hb = wsi[3];
  int g = blockIdx.x * 16 + (threadIdx.x >> 4);
  int c = g >> 7, y = g & 127;
  if (y < by0 || y > by1) return;
  int xs = (threadIdx.x & 15) << 3;
  const float* irow = inp + ((size_t)c * HW + y) * HW;
  const float* mrow = mask + y * HW;
  float acc[8] = {0.f, 0.f, 0.f, 0.f, 0.f, 0.f, 0.f, 0.f};
  #pragma unroll
  for (int tc = 0; tc < 18; ++tc) {
    int x4 = xs - 32 + 4 * tc;
    float vv[4] = {0.f, 0.f, 0.f, 0.f};
    if (x4 >= 0 && x4 <= HW - 4) {
      float4 iv = *(const float4*)(irow + x4);
      float4 mv = *(const float4*)(mrow + x4);
      vv[0] = iv.x * mv.x; vv[1] = iv.y * mv.y; vv[2] = iv.z * mv.z; vv[3] = iv.w * mv.w;
    }
    #pragma unroll
    for (int e = 0; e < 4; ++e) {
      int p = 4 * tc + e;
      #pragma unroll
      for (int a = 0; a < 8; ++a) {
        int j = p - a;
        if (j >= 0 && j <= 64) acc[a] = fmaf(taps[j], vv[e], acc[a]);
      }
    }
  }
  float* trow = tmp + ((size_t)c * Hb + (y - by0)) * HW + xs;
  *(float4*)(trow)     = make_float4(acc[0], acc[1], acc[2], acc[3]);
  *(float4*)(trow + 4) = make_float4(acc[4], acc[5], acc[6], acc[7]);
}

// ---------------------------------------------------------------------------
// Pass B: 65-tap column conv of tmp (bbox-clipped, wave-uniform skip) * rec
// wave = 64 x-lanes, run of 8 consecutive output y's; block = 4 waves
// tasks = C * 16 y-runs * 2 x-halves = 40960 -> 10240 blocks of 4 waves
// ---------------------------------------------------------------------------
__global__ __launch_bounds__(256) void k_colconv(float* __restrict__ out,
                                                 const float* __restrict__ taps,
                                                 const int* __restrict__ wsi,
                                                 const float* __restrict__ rec,
                                                 const float* __restrict__ tmp) {
  int by0 = wsi[0], by1 = wsi[1], Hb = wsi[3];
  int task = __builtin_amdgcn_readfirstlane(blockIdx.x * 4 + (int)(threadIdx.x >> 6));
  int lane = threadIdx.x & 63;
  int xh = task & 1, yr = (task >> 1) & 15, c = task >> 5;
  int y0 = yr << 3;
  int x = (xh << 6) | lane;
  int q0 = by0 - (y0 - 32); if (q0 < 0) q0 = 0;
  int q1 = by1 - (y0 - 32); if (q1 > 71) q1 = 71;
  int r0 = y0 - 32 - by0;  // row offset; r0+q >= 0 whenever q >= q0
  float acc[8] = {0.f, 0.f, 0.f, 0.f, 0.f, 0.f, 0.f, 0.f};
  #pragma unroll
  for (int q = 0; q < 72; ++q) {
    if (q >= q0 && q <= q1) {
      float v = tmp[(size_t)(c * Hb + r0 + q) * HW + x];
      #pragma unroll
      for (int a = 0; a < 8; ++a) {
        int j = q - a;
        if (j >= 0 && j <= 64) acc[a] = fmaf(taps[j], v, acc[a]);
      }
    }
  }
  #pragma unroll
  for (int a = 0; a < 8; ++a) {
    int y = y0 + a;
    out[((size_t)c * HW + y) * HW + x] = acc[a] * rec[y * HW + x];
  }
}

extern "C" void kernel_launch(void* const* d_in, const int* in_sizes, int n_in,
                              void* d_out, int out_size, void* d_ws, size_t ws_size,
                              hipStream_t stream) {
  (void)in_sizes; (void)n_in; (void)out_size; (void)ws_size;
  const float* inp  = (const float*)d_in[0];
  const float* mask = (const float*)d_in[1];  // use channel 0 (all channels identical)
  const float* fw   = (const float*)d_in[3];
  const float* mw   = (const float*)d_in[4];
  const int*   itp  = (const int*)d_in[5];
  float* out = (float*)d_out;
  float* ws  = (float*)d_ws;

  k_setup<<<1, 256, 0, stream>>>(mask, fw, itp, ws);
  k_rowdil<<<HW, HW, 0, stream>>>(mask, ws);
  k_rec<<<HW, HW, 0, stream>>>(mw, ws);
  k_rowconv<<<CCH * HW / 16, 256, 0, stream>>>(inp, mask, ws + OFF_TROW,
                                               (const int*)ws + OFF_INTS, ws + OFF_TMP);
  // tasks = C*16*2 = 40960 waves; 4 waves/block -> 10240 blocks (was /32: half missing!)
  k_colconv<<<CCH * HW / 16, 256, 0, stream>>>(out, ws + OFF_TCOL,
                                               (const int*)ws + OFF_INTS,
                                               ws + OFF_REC, ws + OFF_TMP);
}

// Round 3
// 144.381 us; speedup vs baseline: 1.5901x; 1.5901x over previous
//
#include <hip/hip_runtime.h>

#define HW 128
#define CCH 1280
#define CHUNK 48

// ws float offsets
#define OFF_TROW 0      // 65 x-taps
#define OFF_TCOL 80     // 65 y-taps
#define OFF_INTS 160    // ints: 0 by0, 1 by1, 2 rad, 3 Hb, 4 bx0, 5 bx1, 6 wb
#define OFF_B    256    // 128x128 row-dilated mask
#define OFF_REC  (256 + 16384)  // 128x128 reciprocal denominator

// ---------------------------------------------------------------------------
// Setup: composite 1D taps (iters-fold self-conv of 5-tap marginals) + bbox
// ---------------------------------------------------------------------------
__global__ void k_setup(const float* __restrict__ mask, const float* __restrict__ fw,
                        const int* __restrict__ itp, float* __restrict__ ws) {
  __shared__ float cu[96], cv[96], nu[96], nv[96], su[8], sv[8], sinv[1];
  __shared__ int smn, smx, sxn, sxx;
  int t = threadIdx.x;  // 256 threads
  int iters = itp[0];
  if (iters > 20) iters = 20;
  if (iters < 1) iters = 1;
  if (t == 0) { smn = 1 << 30; smx = -1; sxn = 1 << 30; sxx = -1; }
  if (t < 5) {
    float ru = 0.f, rv = 0.f;
    for (int j = 0; j < 5; ++j) { ru += fw[t * 5 + j]; rv += fw[j * 5 + t]; }
    su[t] = ru; sv[t] = rv;  // rank-1: W = outer(su_y, sv_x)/S
  }
  __syncthreads();
  if (t == 0) {
    float S = su[0] + su[1] + su[2] + su[3] + su[4];
    sinv[0] = (S != 0.f) ? 1.0f / S : 1.0f;
  }
  int mn = 1 << 30, mx = -1, xn = 1 << 30, xx = -1;
  for (int i = t; i < HW * HW; i += 256)
    if (mask[i] > 0.f) {
      int y = i >> 7, xq = i & 127;
      if (y < mn) mn = y; if (y > mx) mx = y;
      if (xq < xn) xn = xq; if (xq > xx) xx = xq;
    }
  __syncthreads();
  if (t < 5) sv[t] *= sinv[0];
  if (mx >= 0) { atomicMin(&smn, mn); atomicMax(&smx, mx);
                 atomicMin(&sxn, xn); atomicMax(&sxx, xx); }
  if (t < 96) { cu[t] = (t == 40) ? 1.f : 0.f; cv[t] = (t == 40) ? 1.f : 0.f; }
  __syncthreads();
  for (int it = 0; it < iters; ++it) {
    if (t < 81) {
      float au = 0.f, av = 0.f;
      #pragma unroll
      for (int i = 0; i < 5; ++i) {
        int s = t - i + 2;
        if (s >= 0 && s <= 80) { au += su[i] * cu[s]; av += sv[i] * cv[s]; }
      }
      nu[t] = au; nv[t] = av;
    }
    __syncthreads();
    if (t < 81) { cu[t] = nu[t]; cv[t] = nv[t]; }
    __syncthreads();
  }
  if (t < 65) { ws[OFF_TCOL + t] = cu[t + 8]; ws[OFF_TROW + t] = cv[t + 8]; }
  if (t == 0) {
    int* wi = (int*)ws + OFF_INTS;
    int by0 = smn, by1 = smx, bx0 = sxn, bx1 = sxx;
    if (by1 < 0) { by0 = 0; by1 = -1; bx0 = 0; bx1 = -1; }
    wi[0] = by0; wi[1] = by1; wi[2] = 2 * (iters - 1); wi[3] = by1 - by0 + 1;
    wi[4] = bx0; wi[5] = bx1; wi[6] = bx1 - bx0 + 1;
  }
}

// ---------------------------------------------------------------------------
// Row dilation of mask channel 0 by +/-rad (binary)
// ---------------------------------------------------------------------------
__global__ void k_rowdil(const float* __restrict__ mask, float* __restrict__ ws) {
  int y = blockIdx.x, x = threadIdx.x;
  int rad = ((const int*)ws)[OFF_INTS + 2];
  const float* row = mask + y * HW;
  int e0 = x - rad; if (e0 < 0) e0 = 0;
  int e1 = x + rad; if (e1 > HW - 1) e1 = HW - 1;
  float s = 0.f;
  for (int e = e0; e <= e1; ++e) s = fmaxf(s, row[e]);
  ws[OFF_B + y * HW + x] = (s > 0.f) ? 1.f : 0.f;
}

// ---------------------------------------------------------------------------
// Column dilation + 5x5 weighted count -> reciprocal denominator table
// ---------------------------------------------------------------------------
__global__ void k_rec(const float* __restrict__ mw, float* __restrict__ ws) {
  __shared__ float m19[5][HW];
  int y = blockIdx.x, x = threadIdx.x;
  int rad = ((const int*)ws)[OFF_INTS + 2];
  const float* b = ws + OFF_B;
  for (int k = 0; k < 5; ++k) {
    int yy = y + k - 2;
    float s = 0.f;
    if (yy >= 0 && yy < HW) {
      int e0 = yy - rad; if (e0 < 0) e0 = 0;
      int e1 = yy + rad; if (e1 > HW - 1) e1 = HW - 1;
      for (int e = e0; e <= e1; ++e) s = fmaxf(s, b[e * HW + x]);
    }
    m19[k][x] = (s > 0.f) ? 1.f : 0.f;
  }
  __syncthreads();
  float msum = 0.f;
  #pragma unroll
  for (int dy = 0; dy < 5; ++dy)
    #pragma unroll
    for (int dx = 0; dx < 5; ++dx) {
      int xx = x + dx - 2;
      if (xx >= 0 && xx < HW) msum += mw[dy * 5 + dx] * m19[dy][xx];
    }
  float d = (msum == 0.f) ? 1.f : msum;
  ws[OFF_REC + y * HW + x] = 1.0f / d;
}

// ---------------------------------------------------------------------------
// Fused per-channel kernel: row conv (bbox cols only) -> LDS tmp -> col conv
// (bbox rows only, chunked by CHUNK) -> * rec -> out.  Tap tables live in LDS
// as 4 parity-shifted copies of zero-padded tables so any 4 consecutive taps
// are one aligned ds_read_b128 and no predication is ever needed.
//   Trow_ext(u') = taps_x[u'-96]  for u' in [96,160], else 0   (u' = x-e+128)
//   Tcol_ext(u') = taps_y[u'-128] for u' in [128,192], else 0  (u' = y-yq+160)
// ---------------------------------------------------------------------------
__global__ __launch_bounds__(256) void k_fused(const float* __restrict__ inp,
                                               const float* __restrict__ mask,
                                               const float* __restrict__ ws,
                                               const float* __restrict__ rec,
                                               float* __restrict__ out) {
  __shared__ __align__(16) float TrowL[4][256];
  __shared__ __align__(16) float TcolL[4][320];
  __shared__ __align__(16) float tmp[CHUNK][HW];

  const int* wsi = (const int*)ws + OFF_INTS;
  int by0 = wsi[0], by1 = wsi[1], bx0 = wsi[4], wb = wsi[6];
  int Hb = (by1 >= by0) ? (by1 - by0 + 1) : 0;
  int c = blockIdx.x;
  int t = threadIdx.x;

  // build parity-replicated padded tap tables: TrowL[p][m] = Trow_ext(m+p)
  for (int i = t; i < 4 * 256; i += 256) {
    int p = i >> 8, m = i & 255;
    int u = m + p - 96;
    TrowL[p][m] = (u >= 0 && u <= 64) ? ws[OFF_TROW + u] : 0.f;
  }
  for (int i = t; i < 4 * 320; i += 256) {
    int p = i / 320, m = i - p * 320;
    int u = m + p - 128;
    TcolL[p][m] = (u >= 0 && u <= 64) ? ws[OFF_TCOL + u] : 0.f;
  }

  int x = t & 127, yh = t >> 7;
  int ybase = yh << 6;                     // this thread owns out rows [ybase, ybase+63] at col x
  float acc[64];
  #pragma unroll
  for (int i = 0; i < 64; ++i) acc[i] = 0.f;

  for (int ch = 0; ch < Hb; ch += CHUNK) {
    int rows = Hb - ch; if (rows > CHUNK) rows = CHUNK;
    __syncthreads();  // tables ready (1st iter) / prev phase-2 done reading tmp

    // ---- phase 1: 65-tap row conv of masked input rows -> tmp[rows][128]
    for (int it = t; it < rows * 16; it += 256) {
      int r = it >> 4, x0 = (it & 15) << 3;
      int ya = by0 + ch + r;
      const float* irow = inp + ((size_t)c * HW + ya) * HW;
      const float* mrow = mask + (size_t)ya * HW;
      float a8[8] = {0.f, 0.f, 0.f, 0.f, 0.f, 0.f, 0.f, 0.f};
      for (int k0 = 0; k0 < wb; k0 += 4) {
        int e0 = bx0 + k0;
        int pbase = x0 - e0 + 125;         // taps for (a,kk): Trow_ext(pbase + a + 3 - kk)
        int pc = pbase < 0 ? 0 : pbase;    // pbase in {-2,-1} => all-zero region; clamp reads zeros
        int p = pc & 3, m0 = pc & ~3;
        float4 w0 = *(const float4*)&TrowL[p][m0];
        float4 w1 = *(const float4*)&TrowL[p][m0 + 4];
        float4 w2 = *(const float4*)&TrowL[p][m0 + 8];
        float w12[12] = {w0.x, w0.y, w0.z, w0.w, w1.x, w1.y, w1.z, w1.w,
                         w2.x, w2.y, w2.z, w2.w};
        #pragma unroll
        for (int kk = 0; kk < 4; ++kk) {
          if (k0 + kk < wb) {
            int e = e0 + kk;
            float v = irow[e] * mrow[e];
            #pragma unroll
            for (int a = 0; a < 8; ++a)
              a8[a] = fmaf(w12[a + 3 - kk], v, a8[a]);
          }
        }
      }
      *(float4*)&tmp[r][x0]     = make_float4(a8[0], a8[1], a8[2], a8[3]);
      *(float4*)&tmp[r][x0 + 4] = make_float4(a8[4], a8[5], a8[6], a8[7]);
    }
    __syncthreads();

    // ---- phase 2: 65-tap col conv, accumulate into acc[64]
    for (int q0 = 0; q0 < rows; q0 += 4) {
      int yq0 = by0 + ch + q0;
      // group contributes to y in [yq0-32, yq0+35]; skip if disjoint (uniform)
      if (yq0 + 35 < ybase || yq0 - 32 > ybase + 63) continue;
      int jbase = ybase - yq0 - 3 + 160;   // >= 30, <= 221
      int p = jbase & 3, m0 = jbase & ~3;
      float w[68];
      #pragma unroll
      for (int i4 = 0; i4 < 17; ++i4) {
        float4 f = *(const float4*)&TcolL[p][m0 + 4 * i4];
        w[4*i4] = f.x; w[4*i4+1] = f.y; w[4*i4+2] = f.z; w[4*i4+3] = f.w;
      }
      #pragma unroll
      for (int qq = 0; qq < 4; ++qq) {
        int q = q0 + qq;
        if (q < rows) {
          float v = tmp[q][x];
          int yq = yq0 + qq;
          int lo = yq - 32 - ybase, hi = yq + 32 - ybase;   // valid yy window
          int c4lo = (lo - 3) >> 2, c4hi = hi >> 2;
          #pragma unroll
          for (int c4 = 0; c4 < 16; ++c4) {
            if (c4 >= c4lo && c4 <= c4hi) {
              int wi = 4 * c4 + 3 - qq;    // tap(yy) = w[yy + 3 - qq]
              acc[4*c4+0] = fmaf(w[wi+0], v, acc[4*c4+0]);
              acc[4*c4+1] = fmaf(w[wi+1], v, acc[4*c4+1]);
              acc[4*c4+2] = fmaf(w[wi+2], v, acc[4*c4+2]);
              acc[4*c4+3] = fmaf(w[wi+3], v, acc[4*c4+3]);
            }
          }
        }
      }
    }
  }

  // ---- epilogue: divide by mask_sum (precomputed reciprocal), write out
  #pragma unroll
  for (int yy = 0; yy < 64; ++yy) {
    int y = ybase + yy;
    out[((size_t)c * HW + y) * HW + x] = acc[yy] * rec[y * HW + x];
  }
}

extern "C" void kernel_launch(void* const* d_in, const int* in_sizes, int n_in,
                              void* d_out, int out_size, void* d_ws, size_t ws_size,
                              hipStream_t stream) {
  (void)in_sizes; (void)n_in; (void)out_size; (void)ws_size;
  const float* inp  = (const float*)d_in[0];
  const float* mask = (const float*)d_in[1];  // channel 0 (all channels identical)
  const float* fw   = (const float*)d_in[3];
  const float* mw   = (const float*)d_in[4];
  const int*   itp  = (const int*)d_in[5];
  float* out = (float*)d_out;
  float* ws  = (float*)d_ws;

  k_setup<<<1, 256, 0, stream>>>(mask, fw, itp, ws);
  k_rowdil<<<HW, HW, 0, stream>>>(mask, ws);
  k_rec<<<HW, HW, 0, stream>>>(mw, ws);
  k_fused<<<CCH, 256, 0, stream>>>(inp, mask, ws, ws + OFF_REC, out);
}

// Round 4
// 73.799 us; speedup vs baseline: 3.1108x; 1.9564x over previous
//
#include <hip/hip_runtime.h>

#define HW 128
#define CCH 1280
#define CHUNK 32
#define TMPS 132   // padded LDS stride for tmp (breaks bank aliasing)

// ws float offsets
#define OFF_TROW 0      // 65 x-taps
#define OFF_TCOL 80     // 65 y-taps
#define OFF_INTS 160    // ints: 0 by0, 1 by1, 2 rad, 3 Hb, 4 bx0, 5 bx1, 6 wb
#define OFF_B    256                 // 128x128 row-dilated mask
#define OFF_C    (256 + 16384)       // 128x128 row+col-dilated mask
#define OFF_REC  (256 + 2 * 16384)   // 128x128 reciprocal denominator

// ---------------------------------------------------------------------------
// Setup: composite 1D taps (iters-fold self-conv of 5-tap marginals) + bbox
// ---------------------------------------------------------------------------
__global__ void k_setup(const float* __restrict__ mask, const float* __restrict__ fw,
                        const int* __restrict__ itp, float* __restrict__ ws) {
  __shared__ float cu[96], cv[96], nu[96], nv[96], su[8], sv[8], sinv[1];
  __shared__ int smn, smx, sxn, sxx;
  int t = threadIdx.x;  // 1024 threads
  int iters = itp[0];
  if (iters > 20) iters = 20;
  if (iters < 1) iters = 1;
  if (t == 0) { smn = 1 << 30; smx = -1; sxn = 1 << 30; sxx = -1; }
  if (t < 5) {
    float ru = 0.f, rv = 0.f;
    for (int j = 0; j < 5; ++j) { ru += fw[t * 5 + j]; rv += fw[j * 5 + t]; }
    su[t] = ru; sv[t] = rv;  // rank-1: W = outer(su_y, sv_x)/S
  }
  __syncthreads();
  if (t == 0) {
    float S = su[0] + su[1] + su[2] + su[3] + su[4];
    sinv[0] = (S != 0.f) ? 1.0f / S : 1.0f;
  }
  int mn = 1 << 30, mx = -1, xn = 1 << 30, xx = -1;
  const float4* m4 = (const float4*)mask;
  for (int i = t; i < HW * HW / 4; i += 1024) {
    float4 v = m4[i];
    float any = fmaxf(fmaxf(v.x, v.y), fmaxf(v.z, v.w));
    if (any > 0.f) {
      int base = i * 4, y = base >> 7, xb = base & 127;
      if (y < mn) mn = y; if (y > mx) mx = y;
      if (v.x > 0.f) { if (xb < xn) xn = xb; if (xb > xx) xx = xb; }
      if (v.y > 0.f) { if (xb+1 < xn) xn = xb+1; if (xb+1 > xx) xx = xb+1; }
      if (v.z > 0.f) { if (xb+2 < xn) xn = xb+2; if (xb+2 > xx) xx = xb+2; }
      if (v.w > 0.f) { if (xb+3 < xn) xn = xb+3; if (xb+3 > xx) xx = xb+3; }
    }
  }
  __syncthreads();
  if (t < 5) sv[t] *= sinv[0];
  if (mx >= 0) { atomicMin(&smn, mn); atomicMax(&smx, mx);
                 atomicMin(&sxn, xn); atomicMax(&sxx, xx); }
  if (t < 96) { cu[t] = (t == 40) ? 1.f : 0.f; cv[t] = (t == 40) ? 1.f : 0.f; }
  __syncthreads();
  for (int it = 0; it < iters; ++it) {
    if (t < 81) {
      float au = 0.f, av = 0.f;
      #pragma unroll
      for (int i = 0; i < 5; ++i) {
        int s = t - i + 2;
        if (s >= 0 && s <= 80) { au += su[i] * cu[s]; av += sv[i] * cv[s]; }
      }
      nu[t] = au; nv[t] = av;
    }
    __syncthreads();
    if (t < 81) { cu[t] = nu[t]; cv[t] = nv[t]; }
    __syncthreads();
  }
  if (t < 65) { ws[OFF_TCOL + t] = cu[t + 8]; ws[OFF_TROW + t] = cv[t + 8]; }
  if (t == 0) {
    int* wi = (int*)ws + OFF_INTS;
    int by0 = smn, by1 = smx, bx0 = sxn, bx1 = sxx;
    if (by1 < 0) { by0 = 0; by1 = -1; bx0 = 0; bx1 = -1; }
    wi[0] = by0; wi[1] = by1; wi[2] = 2 * (iters - 1); wi[3] = by1 - by0 + 1;
    wi[4] = bx0; wi[5] = bx1; wi[6] = bx1 - bx0 + 1;
  }
}

// ---------------------------------------------------------------------------
// Row dilation of mask channel 0 by +/-rad (binary), via LDS row
// ---------------------------------------------------------------------------
__global__ void k_rowdil(const float* __restrict__ mask, float* __restrict__ ws) {
  __shared__ float row[HW];
  int y = blockIdx.x, x = threadIdx.x;
  int rad = ((const int*)ws)[OFF_INTS + 2];
  row[x] = mask[y * HW + x];
  __syncthreads();
  int e0 = x - rad; if (e0 < 0) e0 = 0;
  int e1 = x + rad; if (e1 > HW - 1) e1 = HW - 1;
  float s = 0.f;
  for (int e = e0; e <= e1; ++e) s = fmaxf(s, row[e]);
  ws[OFF_B + y * HW + x] = (s > 0.f) ? 1.f : 0.f;
}

// ---------------------------------------------------------------------------
// Column dilation by +/-rad (coalesced reads of B)
// ---------------------------------------------------------------------------
__global__ void k_coldil(float* __restrict__ ws) {
  int y = blockIdx.x, x = threadIdx.x;
  int rad = ((const int*)ws)[OFF_INTS + 2];
  const float* b = ws + OFF_B;
  int e0 = y - rad; if (e0 < 0) e0 = 0;
  int e1 = y + rad; if (e1 > HW - 1) e1 = HW - 1;
  float s = 0.f;
  for (int e = e0; e <= e1; ++e) s = fmaxf(s, b[e * HW + x]);
  ws[OFF_C + y * HW + x] = (s > 0.f) ? 1.f : 0.f;
}

// ---------------------------------------------------------------------------
// 5x5 weighted count of dilated mask -> reciprocal denominator table
// ---------------------------------------------------------------------------
__global__ void k_rec5(const float* __restrict__ mw, float* __restrict__ ws) {
  int y = blockIdx.x, x = threadIdx.x;
  const float* cdat = ws + OFF_C;
  float msum = 0.f;
  #pragma unroll
  for (int dy = 0; dy < 5; ++dy) {
    int yy = y + dy - 2;
    if (yy >= 0 && yy < HW) {
      #pragma unroll
      for (int dx = 0; dx < 5; ++dx) {
        int xx = x + dx - 2;
        if (xx >= 0 && xx < HW) msum += mw[dy * 5 + dx] * cdat[yy * HW + xx];
      }
    }
  }
  float d = (msum == 0.f) ? 1.f : msum;
  ws[OFF_REC + y * HW + x] = 1.0f / d;
}

// ---------------------------------------------------------------------------
// Fused per-channel kernel.
// Phase 1: 65-tap row conv over bbox cols -> LDS tmp (padded stride).
// Phase 2: 65-tap col conv, zero-padded taps => NO predication; y processed in
//          4 chunks of 16 with a 20-tap register window (5 broadcast b128).
// Thread output ownership: 16 y  x  4 x  => b128 stores.
//   Trow_ext(u') = taps_x[u'-96]  for u' in [96,160], else 0
//   Tcol_ext(u') = taps_y[u'-128] for u' in [128,192], else 0
// ---------------------------------------------------------------------------
__global__ __launch_bounds__(256) void k_fused(const float* __restrict__ inp,
                                               const float* __restrict__ mask,
                                               const float* __restrict__ ws,
                                               const float* __restrict__ rec,
                                               float* __restrict__ out) {
  __shared__ __align__(16) float TrowL[4][256];
  __shared__ __align__(16) float TcolL[4][320];
  __shared__ __align__(16) float tmp[CHUNK][TMPS];

  const int* wsi = (const int*)ws + OFF_INTS;
  int by0 = wsi[0], by1 = wsi[1], bx0 = wsi[4], wb = wsi[6];
  int Hb = (by1 >= by0) ? (by1 - by0 + 1) : 0;
  int c = blockIdx.x;
  int t = threadIdx.x;

  // parity-replicated zero-padded tap tables: T[p][m] = T_ext(m+p)
  for (int i = t; i < 4 * 256; i += 256) {
    int p = i >> 8, m = i & 255;
    int u = m + p - 96;
    TrowL[p][m] = (u >= 0 && u <= 64) ? ws[OFF_TROW + u] : 0.f;
  }
  for (int i = t; i < 4 * 320; i += 256) {
    int p = i / 320, m = i - p * 320;
    int u = m + p - 128;
    TcolL[p][m] = (u >= 0 && u <= 64) ? ws[OFF_TCOL + u] : 0.f;
  }

  int xq = t & 31, yh = t >> 5;       // thread owns y in [yh*16, yh*16+15], x in [xq*4, xq*4+3]
  int x0o = xq << 2, ybase = yh << 4;
  float acc[64];                       // acc[i*4+j] : y = ybase+i, x = x0o+j
  #pragma unroll
  for (int i = 0; i < 64; ++i) acc[i] = 0.f;

  for (int ch = 0; ch < Hb; ch += CHUNK) {
    int rows = Hb - ch; if (rows > CHUNK) rows = CHUNK;
    __syncthreads();  // tables ready (1st iter) / prev phase-2 done with tmp

    // ---- phase 1: row conv of masked input rows -> tmp[rows][128]
    for (int it = t; it < rows * 16; it += 256) {
      int r = it >> 4, x0 = (it & 15) << 3;
      int ya = by0 + ch + r;
      const float* irow = inp + ((size_t)c * HW + ya) * HW;
      const float* mrow = mask + (size_t)ya * HW;
      float a8[8] = {0.f, 0.f, 0.f, 0.f, 0.f, 0.f, 0.f, 0.f};
      for (int k0 = 0; k0 < wb; k0 += 4) {
        int e0 = bx0 + k0;
        int pbase = x0 - e0 + 125;       // taps: Trow_ext(pbase + a + 3 - kk)
        int pc = pbase < 0 ? 0 : pbase;  // pbase>=-2; shift lands in zero margin
        int p = pc & 3, m0 = pc & ~3;
        float4 w0 = *(const float4*)&TrowL[p][m0];
        float4 w1 = *(const float4*)&TrowL[p][m0 + 4];
        float4 w2 = *(const float4*)&TrowL[p][m0 + 8];
        float w12[12] = {w0.x, w0.y, w0.z, w0.w, w1.x, w1.y, w1.z, w1.w,
                         w2.x, w2.y, w2.z, w2.w};
        #pragma unroll
        for (int kk = 0; kk < 4; ++kk) {
          if (k0 + kk < wb) {
            int e = e0 + kk;
            float v = irow[e] * mrow[e];
            #pragma unroll
            for (int a = 0; a < 8; ++a)
              a8[a] = fmaf(w12[a + 3 - kk], v, a8[a]);
          }
        }
      }
      *(float4*)&tmp[r][x0]     = make_float4(a8[0], a8[1], a8[2], a8[3]);
      *(float4*)&tmp[r][x0 + 4] = make_float4(a8[4], a8[5], a8[6], a8[7]);
    }
    __syncthreads();

    // ---- phase 2: col conv, no predication (zero-padded taps)
    int yqb = by0 + ch;
    for (int q0 = 0; q0 < rows; q0 += 4) {
      int yq0 = yqb + q0;
      // this q-group touches y in [yq0-32, yq0+35]; skip if disjoint from our 16
      if (ybase + 15 < yq0 - 32 || ybase > yq0 + 35) continue;
      int jb = ybase - yq0 - 3 + 160;    // in [30, 268]
      int p = jb & 3, m0 = jb & ~3;
      float w20[20];
      #pragma unroll
      for (int i4 = 0; i4 < 5; ++i4) {
        float4 f = *(const float4*)&TcolL[p][m0 + 4 * i4];
        w20[4*i4] = f.x; w20[4*i4+1] = f.y; w20[4*i4+2] = f.z; w20[4*i4+3] = f.w;
      }
      #pragma unroll
      for (int qq = 0; qq < 4; ++qq) {
        if (q0 + qq < rows) {
          float4 v4 = *(const float4*)&tmp[q0 + qq][x0o];
          #pragma unroll
          for (int i = 0; i < 16; ++i) {
            float w = w20[i + 3 - qq];   // tap(y=ybase+i, q)
            acc[i*4+0] = fmaf(w, v4.x, acc[i*4+0]);
            acc[i*4+1] = fmaf(w, v4.y, acc[i*4+1]);
            acc[i*4+2] = fmaf(w, v4.z, acc[i*4+2]);
            acc[i*4+3] = fmaf(w, v4.w, acc[i*4+3]);
          }
        }
      }
    }
  }

  // ---- epilogue: multiply by reciprocal denominator, b128 stores
  #pragma unroll
  for (int i = 0; i < 16; ++i) {
    int y = ybase + i;
    float4 rv = *(const float4*)&rec[y * HW + x0o];
    float4 o = make_float4(acc[i*4+0] * rv.x, acc[i*4+1] * rv.y,
                           acc[i*4+2] * rv.z, acc[i*4+3] * rv.w);
    *(float4*)&out[((size_t)c * HW + y) * HW + x0o] = o;
  }
}

extern "C" void kernel_launch(void* const* d_in, const int* in_sizes, int n_in,
                              void* d_out, int out_size, void* d_ws, size_t ws_size,
                              hipStream_t stream) {
  (void)in_sizes; (void)n_in; (void)out_size; (void)ws_size;
  const float* inp  = (const float*)d_in[0];
  const float* mask = (const float*)d_in[1];  // channel 0 (all channels identical)
  const float* fw   = (const float*)d_in[3];
  const float* mw   = (const float*)d_in[4];
  const int*   itp  = (const int*)d_in[5];
  float* out = (float*)d_out;
  float* ws  = (float*)d_ws;

  k_setup<<<1, 1024, 0, stream>>>(mask, fw, itp, ws);
  k_rowdil<<<HW, HW, 0, stream>>>(mask, ws);
  k_coldil<<<HW, HW, 0, stream>>>(ws);
  k_rec5<<<HW, HW, 0, stream>>>(mw, ws);
  k_fused<<<CCH, 256, 0, stream>>>(inp, mask, ws, ws + OFF_REC, out);
}